// Round 9
// baseline (211.083 us; speedup 1.0000x reference)
//
#include <hip/hip_runtime.h>
#include <math.h>

#define EPS_F 1e-7f

constexpr int Bc = 32, Tc = 8192, Kc = 16;
constexpr int ROWS   = Bc * Tc;            // 262144 rows
constexpr int BLOCK  = 256;
constexpr int NITEM4 = ROWS * 4;           // 1048576 vec4 items (4 slots each)
constexpr int UNROLL = 4;                  // items per thread (consecutive chunks)
constexpr int NBLK   = NITEM4 / (BLOCK * UNROLL);  // 1024 blocks

typedef unsigned long long u64;

__device__ __forceinline__ u64 shflx64(u64 v, int m) {
  unsigned lo = __shfl_xor((unsigned)v, m, 64);
  unsigned hi = __shfl_xor((unsigned)(v >> 32), m, 64);
  return ((u64)hi << 32) | lo;
}

// One item's worth of loaded data (13 vec4 + 2 row scalars).
struct Tile {
  int4   oc, cc, cd, lm;
  float4 ff, vv, ph, pq, lA, lB, lC;
  float  wx, wy;
};

struct Ptrs {
  const char *trig, *valp, *clog, *wscore, *live, *cid;
  const char *ofire, *ocan, *ovalid, *oshw, *ocid;
};

__device__ __forceinline__ void load_tile(Tile& T, const Ptrs& P, int gi) {
  const size_t o16 = (size_t)gi * 16;
  const size_t o48 = (size_t)gi * 48;
  T.oc = *(const int4*)  (P.ocid   + o16);
  T.cc = *(const int4*)  (P.ocan   + o16);
  T.ff = *(const float4*)(P.ofire  + o16);
  T.vv = *(const float4*)(P.ovalid + o16);
  T.cd = *(const int4*)  (P.cid    + o16);
  T.lm = *(const int4*)  (P.live   + o16);
  T.ph = *(const float4*)(P.trig   + o16);
  T.pq = *(const float4*)(P.valp   + o16);
  T.lA = *(const float4*)(P.clog   + o48 + 0);
  T.lB = *(const float4*)(P.clog   + o48 + 16);
  T.lC = *(const float4*)(P.clog   + o48 + 32);
  const size_t ro = (size_t)(gi >> 2) * 4;
  T.wx = *(const float*)(P.wscore + ro);
  T.wy = *(const float*)(P.oshw   + ro);
}

// Proven compute path (absmax=0.0 in R2/R4/R7/R8): per-lane partial oracle
// table -> 4-lane shuffle merge (lower lane = earlier slot wins) -> losses.
__device__ __forceinline__ void compute_tile(
    const Tile& T, int tid, int lane, float a[6])
{
  u64 tblLo = 0ull, tblHi = 0ull, fndLo = 0ull, fndHi = 0ull;
  {
    const int   ocs[4] = {T.oc.x, T.oc.y, T.oc.z, T.oc.w};
    const int   ccs[4] = {T.cc.x, T.cc.y, T.cc.z, T.cc.w};
    const float ffs[4] = {T.ff.x, T.ff.y, T.ff.z, T.ff.w};
    const float vvs[4] = {T.vv.x, T.vv.y, T.vv.z, T.vv.w};
    #pragma unroll
    for (int j = 0; j < 4; ++j) {
      const unsigned c  = (unsigned)ocs[j] & 31u;
      const unsigned sh = (c & 15u) * 4u;
      const bool isLo   = c < 16u;
      const bool seen   = (((isLo ? fndLo : fndHi) >> sh) & 1ull) != 0ull;
      const unsigned nib = (unsigned)ffs[j] | ((unsigned)vvs[j] << 1) |
                           ((unsigned)ccs[j] << 2);
      const u64 add  = seen ? 0ull : ((u64)nib << sh);
      const u64 fadd = 0xFull << sh;
      tblLo |= isLo ? add : 0ull;
      tblHi |= isLo ? 0ull : add;
      fndLo |= isLo ? fadd : 0ull;
      fndHi |= isLo ? 0ull : fadd;
    }
  }

  #pragma unroll
  for (int m = 1; m <= 2; m <<= 1) {
    const u64 pTL = shflx64(tblLo, m);
    const u64 pTH = shflx64(tblHi, m);
    const u64 pFL = shflx64(fndLo, m);
    const u64 pFH = shflx64(fndHi, m);
    const bool iLow = (lane & m) == 0;
    const u64 loTL = iLow ? tblLo : pTL, hiTL = iLow ? pTL : tblLo;
    const u64 loTH = iLow ? tblHi : pTH, hiTH = iLow ? pTH : tblHi;
    const u64 loFL = iLow ? fndLo : pFL, hiFL = iLow ? pFL : fndLo;
    const u64 loFH = iLow ? fndHi : pFH, hiFH = iLow ? pFH : fndHi;
    tblLo = loTL | (hiTL & ~loFL);
    tblHi = loTH | (hiTH & ~loFH);
    fndLo = loFL | hiFL;
    fndHi = loFH | hiFH;
  }

  {
    const int   cds[4] = {T.cd.x, T.cd.y, T.cd.z, T.cd.w};
    const int   lms[4] = {T.lm.x, T.lm.y, T.lm.z, T.lm.w};
    const float phs[4] = {T.ph.x, T.ph.y, T.ph.z, T.ph.w};
    const float pqs[4] = {T.pq.x, T.pq.y, T.pq.z, T.pq.w};
    const float L0[4] = {T.lA.x, T.lA.w, T.lB.z, T.lC.y};
    const float L1[4] = {T.lA.y, T.lB.x, T.lB.w, T.lC.z};
    const float L2[4] = {T.lA.z, T.lB.y, T.lC.x, T.lC.w};
    #pragma unroll
    for (int j = 0; j < 4; ++j) {
      const unsigned c  = (unsigned)cds[j] & 31u;
      const unsigned sh = (c & 15u) * 4u;
      const bool isLo   = c < 16u;
      const bool fnd = (c != 0u) &&
                       ((((isLo ? fndLo : fndHi) >> sh) & 1ull) != 0ull);
      unsigned nib = (unsigned)(((isLo ? tblLo : tblHi) >> sh)) & 15u;
      nib = fnd ? nib : 0u;
      const float fire_t = (float)(nib & 1u);
      const float val_t  = (float)((nib >> 1) & 1u);
      const int   can_t  = (int)(nib >> 2);

      const float m = lms[j] ? 1.f : 0.f;

      const float p  = fminf(fmaxf(phs[j], EPS_F), 1.f - EPS_F);
      const float bf = -__logf((fire_t != 0.f) ? p : 1.f - p);
      const float q  = fminf(fmaxf(pqs[j], EPS_F), 1.f - EPS_F);
      const float bv = -__logf((val_t != 0.f) ? q : 1.f - q);

      const float has = (can_t > 0 && lms[j]) ? 1.f : 0.f;
      const int tgt = (can_t - 1) < 0 ? 0 : (can_t - 1);
      const float l0 = L0[j], l1 = L1[j], l2 = L2[j];
      const float mx  = fmaxf(l0, fmaxf(l1, l2));
      const float lse = mx + __logf(__expf(l0 - mx) + __expf(l1 - mx) +
                                    __expf(l2 - mx));
      const float lt  = (tgt == 0) ? l0 : ((tgt == 1) ? l1 : l2);

      a[0] += bf * m;
      a[1] += m;
      a[2] += (lse - lt) * has;
      a[3] += has;
      a[4] += bv * m;
    }
  }

  if ((tid & 3) == 0) {
    a[5] += fmaxf(T.wx, 0.f) - T.wx * T.wy +
            __logf(1.f + __expf(-fabsf(T.wx)));
  }
}

// Service-rate-oriented layout: each block owns a CONTIGUOUS 1024-item span
// (16KB per array), walked as 4 consecutive 1KB wave-bursts per array via a
// depth-2 register pipeline (static A/B tiles -> no dynamic indexing, no
// scratch). 4x fewer active blocks + 4x longer per-array runs = better DRAM
// page/channel locality; A/B overlap keeps a full 13-load tile in flight
// during each compute phase.
__global__ __launch_bounds__(BLOCK) void loss_main(
    const float* __restrict__ trig,
    const float* __restrict__ valp,
    const float* __restrict__ clog,
    const float* __restrict__ wscore,
    const int*   __restrict__ live,
    const int*   __restrict__ cid,
    const float* __restrict__ ofire,
    const int*   __restrict__ ocan,
    const float* __restrict__ ovalid,
    const float* __restrict__ oshw,
    const int*   __restrict__ ocid,
    float* __restrict__ part)            // [NBLK][6]
{
  const int tid  = threadIdx.x;
  const int lane = tid & 63;
  const int gi0  = blockIdx.x * (BLOCK * UNROLL) + tid;

  Ptrs P;
  P.trig = (const char*)trig;   P.valp   = (const char*)valp;
  P.clog = (const char*)clog;   P.wscore = (const char*)wscore;
  P.live = (const char*)live;   P.cid    = (const char*)cid;
  P.ofire= (const char*)ofire;  P.ocan   = (const char*)ocan;
  P.ovalid=(const char*)ovalid; P.oshw   = (const char*)oshw;
  P.ocid = (const char*)ocid;

  float a[6] = {0.f, 0.f, 0.f, 0.f, 0.f, 0.f};

  // depth-2 register pipeline, statically named tiles (rule #20)
  Tile A, B;
  load_tile(A, P, gi0 + 0 * BLOCK);
  load_tile(B, P, gi0 + 1 * BLOCK);
  compute_tile(A, tid, lane, a);           // u=0 (B's loads in flight)
  load_tile(A, P, gi0 + 2 * BLOCK);
  compute_tile(B, tid, lane, a);           // u=1 (A's loads in flight)
  load_tile(B, P, gi0 + 3 * BLOCK);
  compute_tile(A, tid, lane, a);           // u=2 (B's loads in flight)
  compute_tile(B, tid, lane, a);           // u=3

  // ---- wave reduce, then block reduce via LDS
  #pragma unroll
  for (int off = 32; off > 0; off >>= 1) {
    #pragma unroll
    for (int i = 0; i < 6; ++i) a[i] += __shfl_down(a[i], off, 64);
  }
  __shared__ float red[4][6];
  const int w = tid >> 6;
  if (lane == 0) {
    #pragma unroll
    for (int i = 0; i < 6; ++i) red[w][i] = a[i];
  }
  __syncthreads();
  if (tid == 0) {
    #pragma unroll
    for (int i = 0; i < 6; ++i)
      part[blockIdx.x * 6 + i] = red[0][i] + red[1][i] + red[2][i] + red[3][i];
  }
}

// Reduce NBLK partials in double, compute the 5 outputs.
__global__ __launch_bounds__(BLOCK) void loss_finalize(
    const float* __restrict__ part, float* __restrict__ out)
{
  double v[6] = {0, 0, 0, 0, 0, 0};
  for (int r = threadIdx.x; r < NBLK; r += BLOCK) {
    #pragma unroll
    for (int i = 0; i < 6; ++i) v[i] += (double)part[r * 6 + i];
  }
  #pragma unroll
  for (int off = 32; off > 0; off >>= 1) {
    #pragma unroll
    for (int i = 0; i < 6; ++i) v[i] += __shfl_down(v[i], off, 64);
  }
  __shared__ double red[4][6];
  const int w = threadIdx.x >> 6, lane = threadIdx.x & 63;
  if (lane == 0) {
    #pragma unroll
    for (int i = 0; i < 6; ++i) red[w][i] = v[i];
  }
  __syncthreads();
  if (threadIdx.x == 0) {
    double a[6];
    #pragma unroll
    for (int i = 0; i < 6; ++i) a[i] = red[0][i] + red[1][i] + red[2][i] + red[3][i];
    const double live_n = a[1] < 1.0 ? 1.0 : a[1];
    const double fire   = a[0] / live_n;                                   // LAM_FIRE   = 1.0
    const double cancel = (a[3] > 0.0) ? a[2] / (a[3] < 1.0 ? 1.0 : a[3])  // LAM_CANCEL = 1.0
                                       : 0.0;
    const double valid  = 0.5 * a[4] / live_n;                             // LAM_VALID  = 0.5
    const double wr     = 0.5 * a[5] / (double)ROWS;                       // LAM_WRITE  = 0.5
    out[0] = (float)fire;
    out[1] = (float)cancel;
    out[2] = (float)valid;
    out[3] = (float)wr;
    out[4] = (float)(fire + cancel + valid + wr);
  }
}

extern "C" void kernel_launch(void* const* d_in, const int* in_sizes, int n_in,
                              void* d_out, int out_size, void* d_ws, size_t ws_size,
                              hipStream_t stream) {
  const float* trig   = (const float*)d_in[0];
  const float* valp   = (const float*)d_in[1];
  const float* clog   = (const float*)d_in[2];
  const float* wscore = (const float*)d_in[3];
  const int*   live   = (const int*)  d_in[4];
  const int*   cid    = (const int*)  d_in[5];
  const float* ofire  = (const float*)d_in[6];
  const int*   ocan   = (const int*)  d_in[7];
  const float* ovalid = (const float*)d_in[8];
  const float* oshw   = (const float*)d_in[9];
  const int*   ocid   = (const int*)  d_in[10];
  float* out  = (float*)d_out;
  float* part = (float*)d_ws;   // NBLK*6 floats = 24 KB, fully overwritten

  loss_main<<<NBLK, BLOCK, 0, stream>>>(trig, valp, clog, wscore, live, cid,
                                        ofire, ocan, ovalid, oshw, ocid, part);
  loss_finalize<<<1, BLOCK, 0, stream>>>(part, out);
}